// Round 1
// baseline (859.609 us; speedup 1.0000x reference)
//
#include <hip/hip_runtime.h>
#include <math.h>

#define HD 1024
#define ED 2048
#define NL 4
#define OUTN 50257

__device__ __forceinline__ float wave_reduce_sum(float v) {
    #pragma unroll
    for (int off = 32; off > 0; off >>= 1)
        v += __shfl_xor(v, off, 64);
    return v;
}

// One wave per (direction d, hidden unit j): computes
//   gi_{r,z,n} = w_ih[d][{j,H+j,2H+j}] . x        (len E)
//   gh_{r,z,n} = w_hh[d][{j,H+j,2H+j}] . h_prev_d (len H)
// then gates + h_new on lane 0.
__global__ __launch_bounds__(256) void gru_layer_k(
    const float* __restrict__ w_ih,   // (2,3H,E) layer base
    const float* __restrict__ w_hh,   // (2,3H,H) layer base
    const float* __restrict__ b_ih,   // (2,3H)
    const float* __restrict__ b_hh,   // (2,3H)
    const float* __restrict__ h_prev, // (2,H) = hidden + l*2*H
    const float* __restrict__ embed,  // embed table (layer 0) or nullptr
    const int*  __restrict__ feat,    // token index (layer 0) or nullptr
    const float* __restrict__ x_in,   // ws x buffer (2048), layers >= 1
    float* __restrict__ x_out,        // ws x buffer (2048)
    float* __restrict__ h_out)        // d_out + OUTN + l*2*H
{
    const int wv   = (blockIdx.x * blockDim.x + threadIdx.x) >> 6; // 0..2047
    const int lane = threadIdx.x & 63;
    const int d    = wv >> 10;        // direction 0/1
    const int j    = wv & (HD - 1);   // hidden unit

    const float* x = feat ? (embed + (size_t)feat[0] * ED) : x_in;

    // ---- input-hidden: 3 rows of length E ----
    const float* wr = w_ih + ((size_t)(d * 3 * HD) + j) * ED;
    const float* wz = wr + (size_t)HD * ED;
    const float* wn = wz + (size_t)HD * ED;

    float ar = 0.f, az = 0.f, an = 0.f;
    #pragma unroll
    for (int it = 0; it < ED / 256; ++it) {
        const int idx = it * 256 + lane * 4;
        const float4 xv = *(const float4*)(x + idx);
        const float4 r4 = *(const float4*)(wr + idx);
        const float4 z4 = *(const float4*)(wz + idx);
        const float4 n4 = *(const float4*)(wn + idx);
        ar += r4.x * xv.x + r4.y * xv.y + r4.z * xv.z + r4.w * xv.w;
        az += z4.x * xv.x + z4.y * xv.y + z4.z * xv.z + z4.w * xv.w;
        an += n4.x * xv.x + n4.y * xv.y + n4.z * xv.z + n4.w * xv.w;
    }

    // ---- hidden-hidden: 3 rows of length H ----
    const float* hvec = h_prev + d * HD;
    const float* ur = w_hh + ((size_t)(d * 3 * HD) + j) * HD;
    const float* uz = ur + (size_t)HD * HD;
    const float* un = uz + (size_t)HD * HD;

    float hr = 0.f, hz = 0.f, hn = 0.f;
    #pragma unroll
    for (int it = 0; it < HD / 256; ++it) {
        const int idx = it * 256 + lane * 4;
        const float4 hv = *(const float4*)(hvec + idx);
        const float4 r4 = *(const float4*)(ur + idx);
        const float4 z4 = *(const float4*)(uz + idx);
        const float4 n4 = *(const float4*)(un + idx);
        hr += r4.x * hv.x + r4.y * hv.y + r4.z * hv.z + r4.w * hv.w;
        hz += z4.x * hv.x + z4.y * hv.y + z4.z * hv.z + z4.w * hv.w;
        hn += n4.x * hv.x + n4.y * hv.y + n4.z * hv.z + n4.w * hv.w;
    }

    ar = wave_reduce_sum(ar);
    az = wave_reduce_sum(az);
    an = wave_reduce_sum(an);
    hr = wave_reduce_sum(hr);
    hz = wave_reduce_sum(hz);
    hn = wave_reduce_sum(hn);

    if (lane == 0) {
        const int g = d * 3 * HD;
        const float i_r = ar + b_ih[g + j];
        const float i_z = az + b_ih[g + HD + j];
        const float i_n = an + b_ih[g + 2 * HD + j];
        const float h_r = hr + b_hh[g + j];
        const float h_z = hz + b_hh[g + HD + j];
        const float h_n = hn + b_hh[g + 2 * HD + j];
        const float r = 1.f / (1.f + __expf(-(i_r + h_r)));
        const float z = 1.f / (1.f + __expf(-(i_z + h_z)));
        const float n = tanhf(i_n + r * h_n);
        const float hp = hvec[j];
        const float hnew = (1.f - z) * n + z * hp;
        h_out[d * HD + j] = hnew;
        x_out[d * HD + j] = hnew;
    }
}

// One wave per output row: out[o] = fc_w[o] . x + fc_b[o]
__global__ __launch_bounds__(256) void fc_k(
    const float* __restrict__ fc_w,  // (O, 2H)
    const float* __restrict__ fc_b,  // (O,)
    const float* __restrict__ x,     // (2H,) last-layer output (ws, aligned)
    float* __restrict__ out)         // (O,)
{
    const int wv   = (blockIdx.x * blockDim.x + threadIdx.x) >> 6;
    const int lane = threadIdx.x & 63;
    if (wv >= OUTN) return;

    const float* wrow = fc_w + (size_t)wv * (2 * HD);
    float acc = 0.f;
    #pragma unroll
    for (int it = 0; it < (2 * HD) / 256; ++it) {
        const int idx = it * 256 + lane * 4;
        const float4 w4 = *(const float4*)(wrow + idx);
        const float4 x4 = *(const float4*)(x + idx);
        acc += w4.x * x4.x + w4.y * x4.y + w4.z * x4.z + w4.w * x4.w;
    }
    acc = wave_reduce_sum(acc);
    if (lane == 0) out[wv] = acc + fc_b[wv];
}

extern "C" void kernel_launch(void* const* d_in, const int* in_sizes, int n_in,
                              void* d_out, int out_size, void* d_ws, size_t ws_size,
                              hipStream_t stream) {
    const int*   feat   = (const int*)  d_in[0];
    const float* hidden = (const float*)d_in[1];
    const float* embed  = (const float*)d_in[2];
    const float* w_ih   = (const float*)d_in[3];
    const float* w_hh   = (const float*)d_in[4];
    const float* b_ih   = (const float*)d_in[5];
    const float* b_hh   = (const float*)d_in[6];
    const float* fc_w   = (const float*)d_in[7];
    const float* fc_b   = (const float*)d_in[8];
    float* out  = (float*)d_out;
    float* xbuf = (float*)d_ws;   // two ping-pong x buffers of ED floats

    // Layer l writes xbuf[l&1]; reads xbuf[(l-1)&1] (l>=1). FC reads xbuf[1].
    for (int l = 0; l < NL; ++l) {
        gru_layer_k<<<2 * HD * 64 / 256, 256, 0, stream>>>(
            w_ih + (size_t)l * 2 * 3 * HD * ED,
            w_hh + (size_t)l * 2 * 3 * HD * HD,
            b_ih + (size_t)l * 2 * 3 * HD,
            b_hh + (size_t)l * 2 * 3 * HD,
            hidden + (size_t)l * 2 * HD,
            (l == 0) ? embed : nullptr,
            (l == 0) ? feat  : nullptr,
            xbuf + (size_t)((l + 1) & 1) * ED,
            xbuf + (size_t)(l & 1) * ED,
            out + OUTN + (size_t)l * 2 * HD);
    }

    const int fc_waves_per_block = 256 / 64;
    const int fc_blocks = (OUTN + fc_waves_per_block - 1) / fc_waves_per_block;
    fc_k<<<fc_blocks, 256, 0, stream>>>(fc_w, fc_b, xbuf + ED, out);
}